// Round 3
// baseline (2366.083 us; speedup 1.0000x reference)
//
#include <hip/hip_runtime.h>

#define THREADS 256
#define NB 128          // nodes per bucket
#define KMAX 800        // >= ceil(N/NB)
#define NCHUNK 256      // edge chunks for bucket sort

// ---------------------------------------------------------------------------
// Pipeline:
//  detect -> zero(deg) -> hist(deg atomics + per-(chunk,bucket) histogram)
//  -> colscan (per-bucket chunk prefix) -> basescan (bucket bases)
//  -> dinv -> passB (bucketed packed edge list) -> gemm1 -> bagg1(LDS tile)
//  -> gemm2 -> bagg2(LDS tile, writes d_out)
// packed edge = (src << 7) | (dst & 127); bucket = dst >> 7
// ---------------------------------------------------------------------------

__global__ void k_detect(const int* __restrict__ e32, int* __restrict__ flag) {
    if (blockIdx.x == 0 && threadIdx.x == 0) {
        int st = 2;
        for (int i = 0; i < 64; ++i)
            if (e32[2 * i + 1] != 0) { st = 1; break; }
        *flag = st;
    }
}

__global__ __launch_bounds__(THREADS) void k_zero_int(int* __restrict__ p, int n) {
    int i = blockIdx.x * THREADS + threadIdx.x;
    if (i < n) p[i] = 0;
}

// deg[dst]++ (global) and per-chunk bucket histogram (LDS -> H[chunk][K])
__global__ __launch_bounds__(THREADS) void k_hist(const int* __restrict__ eidx,
                                                  const int* __restrict__ flag,
                                                  int E, int C, int K,
                                                  int* __restrict__ deg,
                                                  int* __restrict__ H) {
    __shared__ int hl[KMAX];
    int st = *flag;
    for (int i = threadIdx.x; i < K; i += THREADS) hl[i] = 0;
    __syncthreads();
    int s0 = blockIdx.x * C;
    int s1 = min(s0 + C, E);
    for (int e = s0 + threadIdx.x; e < s1; e += THREADS) {
        int d = eidx[(size_t)(E + e) * st];
        atomicAdd(&deg[d], 1);
        atomicAdd(&hl[d >> 7], 1);
    }
    __syncthreads();
    for (int i = threadIdx.x; i < K; i += THREADS)
        H[(size_t)blockIdx.x * K + i] = hl[i];
}

// per-bucket exclusive prefix over chunks (in place); btot = bucket totals
__global__ __launch_bounds__(THREADS) void k_colscan(int* __restrict__ H,
                                                     int* __restrict__ btot,
                                                     int K, int nchunk) {
    int t = blockIdx.x * THREADS + threadIdx.x;
    if (t >= K) return;
    int run = 0;
    for (int c = 0; c < nchunk; ++c) {
        int v = H[(size_t)c * K + t];
        H[(size_t)c * K + t] = run;
        run += v;
    }
    btot[t] = run;
}

// exclusive scan of bucket totals -> base[0..K]
__global__ __launch_bounds__(1024) void k_basescan(const int* __restrict__ btot,
                                                   int* __restrict__ base, int K) {
    __shared__ int s[1024];
    int v = (threadIdx.x < (unsigned)K) ? btot[threadIdx.x] : 0;
    s[threadIdx.x] = v;
    __syncthreads();
    for (int off = 1; off < 1024; off <<= 1) {
        int t = (threadIdx.x >= off) ? s[threadIdx.x - off] : 0;
        __syncthreads();
        s[threadIdx.x] += t;
        __syncthreads();
    }
    if (threadIdx.x < (unsigned)K) {
        base[threadIdx.x] = s[threadIdx.x] - v;
        if (threadIdx.x == K - 1) base[K] = s[threadIdx.x];
    }
}

__global__ __launch_bounds__(THREADS) void k_dinv(const int* __restrict__ deg,
                                                  float* __restrict__ dinv, int n) {
    int i = blockIdx.x * THREADS + threadIdx.x;
    if (i < n) dinv[i] = rsqrtf((float)deg[i] + 1.0f);
}

// scatter packed edges to bucket-sorted positions (LDS cursors)
__global__ __launch_bounds__(THREADS) void k_passB(const int* __restrict__ eidx,
                                                   const int* __restrict__ flag,
                                                   int E, int C, int K,
                                                   const int* __restrict__ H,
                                                   const int* __restrict__ base,
                                                   unsigned int* __restrict__ packed) {
    __shared__ int cur[KMAX];
    int st = *flag;
    for (int i = threadIdx.x; i < K; i += THREADS)
        cur[i] = base[i] + H[(size_t)blockIdx.x * K + i];
    __syncthreads();
    int s0 = blockIdx.x * C;
    int s1 = min(s0 + C, E);
    for (int e = s0 + threadIdx.x; e < s1; e += THREADS) {
        int s = eidx[(size_t)e * st];
        int d = eidx[(size_t)(E + e) * st];
        int pos = atomicAdd(&cur[d >> 7], 1);
        packed[pos] = ((unsigned)s << 7) | (unsigned)(d & 127);
    }
}

// g1[r,c] = (x[r,:] @ W1[:,c]) * dinv[r]
__global__ __launch_bounds__(THREADS) void k_gemm1(const float* __restrict__ x,
                                                   const float* __restrict__ W1,
                                                   const float* __restrict__ dinv,
                                                   float* __restrict__ g1, int N) {
    __shared__ float Wl[128 * 64];
    for (int i = threadIdx.x; i < 128 * 64; i += THREADS) Wl[i] = W1[i];
    __syncthreads();
    int c = threadIdx.x & 63;
    int rloc = threadIdx.x >> 6;  // 0..3
    for (int rb = blockIdx.x; rb * 4 < N; rb += gridDim.x) {
        int r = rb * 4 + rloc;
        if (r < N) {
            const float4* xr = (const float4*)(x + (size_t)r * 128);
            float acc = 0.0f;
#pragma unroll
            for (int k4 = 0; k4 < 32; ++k4) {
                float4 xv = xr[k4];
                acc = fmaf(xv.x, Wl[(k4 * 4 + 0) * 64 + c], acc);
                acc = fmaf(xv.y, Wl[(k4 * 4 + 1) * 64 + c], acc);
                acc = fmaf(xv.z, Wl[(k4 * 4 + 2) * 64 + c], acc);
                acc = fmaf(xv.w, Wl[(k4 * 4 + 3) * 64 + c], acc);
            }
            g1[(size_t)r * 64 + c] = acc * dinv[r];
        }
    }
}

// bucket aggregation layer1: LDS tile 128x64, LDS atomics; fused epilogue
__global__ __launch_bounds__(THREADS) void k_bagg1(const unsigned int* __restrict__ packed,
                                                   const int* __restrict__ base,
                                                   const float* __restrict__ g1,
                                                   const float* __restrict__ dinv,
                                                   const float* __restrict__ b1,
                                                   float* __restrict__ h1, int N) {
    __shared__ float tile[128 * 64];
    for (int i = threadIdx.x; i < 128 * 64; i += THREADS) tile[i] = 0.0f;
    __syncthreads();
    int b = blockIdx.x;
    int lane = threadIdx.x & 63;
    int wv = threadIdx.x >> 6;  // 0..3
    int j = base[b] + wv;
    int end = base[b + 1];
    for (; j + 4 < end; j += 8) {
        unsigned e0 = packed[j];
        unsigned e1 = packed[j + 4];
        float v0 = g1[(size_t)(e0 >> 7) * 64 + lane];
        float v1 = g1[(size_t)(e1 >> 7) * 64 + lane];
        atomicAdd(&tile[(e0 & 127u) * 64 + lane], v0);
        atomicAdd(&tile[(e1 & 127u) * 64 + lane], v1);
    }
    if (j < end) {
        unsigned e0 = packed[j];
        atomicAdd(&tile[(e0 & 127u) * 64 + lane], g1[(size_t)(e0 >> 7) * 64 + lane]);
    }
    __syncthreads();
    float bb = b1[lane];
    for (int r = wv; r < 128; r += 4) {
        int v = b * NB + r;
        if (v < N) {
            float self = g1[(size_t)v * 64 + lane];
            h1[(size_t)v * 64 + lane] =
                fmaxf(fmaf(dinv[v], tile[r * 64 + lane] + self, bb), 0.0f);
        }
    }
}

// g2[r,c] = (h1[r,:] @ W2[:,c]) * dinv[r]
__global__ __launch_bounds__(THREADS) void k_gemm2(const float* __restrict__ h1,
                                                   const float* __restrict__ W2,
                                                   const float* __restrict__ dinv,
                                                   float* __restrict__ g2, int N) {
    __shared__ float Wl[64 * 32];
    for (int i = threadIdx.x; i < 64 * 32; i += THREADS) Wl[i] = W2[i];
    __syncthreads();
    int c = threadIdx.x & 31;
    int rloc = threadIdx.x >> 5;  // 0..7
    for (int rb = blockIdx.x; rb * 8 < N; rb += gridDim.x) {
        int r = rb * 8 + rloc;
        if (r < N) {
            const float4* ar = (const float4*)(h1 + (size_t)r * 64);
            float acc = 0.0f;
#pragma unroll
            for (int k4 = 0; k4 < 16; ++k4) {
                float4 hv = ar[k4];
                acc = fmaf(hv.x, Wl[(k4 * 4 + 0) * 32 + c], acc);
                acc = fmaf(hv.y, Wl[(k4 * 4 + 1) * 32 + c], acc);
                acc = fmaf(hv.z, Wl[(k4 * 4 + 2) * 32 + c], acc);
                acc = fmaf(hv.w, Wl[(k4 * 4 + 3) * 32 + c], acc);
            }
            g2[(size_t)r * 32 + c] = acc * dinv[r];
        }
    }
}

// bucket aggregation layer2: LDS tile 128x32; writes final output
__global__ __launch_bounds__(THREADS) void k_bagg2(const unsigned int* __restrict__ packed,
                                                   const int* __restrict__ base,
                                                   const float* __restrict__ g2,
                                                   const float* __restrict__ dinv,
                                                   const float* __restrict__ b2,
                                                   float* __restrict__ out, int N) {
    __shared__ float tile[128 * 32];
    for (int i = threadIdx.x; i < 128 * 32; i += THREADS) tile[i] = 0.0f;
    __syncthreads();
    int b = blockIdx.x;
    int lane = threadIdx.x & 31;
    int g = threadIdx.x >> 5;  // 0..7
    int j = base[b] + g;
    int end = base[b + 1];
    for (; j + 8 < end; j += 16) {
        unsigned e0 = packed[j];
        unsigned e1 = packed[j + 8];
        float v0 = g2[(size_t)(e0 >> 7) * 32 + lane];
        float v1 = g2[(size_t)(e1 >> 7) * 32 + lane];
        atomicAdd(&tile[(e0 & 127u) * 32 + lane], v0);
        atomicAdd(&tile[(e1 & 127u) * 32 + lane], v1);
    }
    if (j < end) {
        unsigned e0 = packed[j];
        atomicAdd(&tile[(e0 & 127u) * 32 + lane], g2[(size_t)(e0 >> 7) * 32 + lane]);
    }
    __syncthreads();
    float bb = b2[lane];
    for (int r = g; r < 128; r += 8) {
        int v = b * NB + r;
        if (v < N) {
            float self = g2[(size_t)v * 32 + lane];
            out[(size_t)v * 32 + lane] = fmaf(dinv[v], tile[r * 32 + lane] + self, bb);
        }
    }
}

extern "C" void kernel_launch(void* const* d_in, const int* in_sizes, int n_in,
                              void* d_out, int out_size, void* d_ws, size_t ws_size,
                              hipStream_t stream) {
    const float* x  = (const float*)d_in[0];
    const int* eidx = (const int*)d_in[1];
    const float* W1 = (const float*)d_in[2];
    const float* b1 = (const float*)d_in[3];
    const float* W2 = (const float*)d_in[4];
    const float* b2 = (const float*)d_in[5];
    float* out = (float*)d_out;

    const int N = in_sizes[0] / 128;   // 100000
    const int E = in_sizes[1] / 2;     // 3200000
    const int K = (N + NB - 1) / NB;   // 782
    const int C = (E + NCHUNK - 1) / NCHUNK;

    // ws layout (ints after 64-byte header)
    int* flag   = (int*)d_ws;
    int* deg    = (int*)d_ws + 16;
    int* H      = deg + N;                      // NCHUNK*K
    int* btot   = H + (size_t)NCHUNK * K;       // K
    int* base   = btot + K;                     // K+1
    unsigned int* packed = (unsigned int*)(base + K + 1);  // E
    float* dinv = (float*)(packed + E);
    float* g1   = dinv + N;                     // N*64
    float* h1   = g1 + (size_t)N * 64;          // N*64
    float* g2   = g1;                           // alias: g1 dead after bagg1

    int nblkN = (N + THREADS - 1) / THREADS;
    int nblkK = (K + THREADS - 1) / THREADS;

    k_detect<<<1, 64, 0, stream>>>(eidx, flag);
    k_zero_int<<<nblkN, THREADS, 0, stream>>>(deg, N);
    k_hist<<<NCHUNK, THREADS, 0, stream>>>(eidx, flag, E, C, K, deg, H);
    k_colscan<<<nblkK, THREADS, 0, stream>>>(H, btot, K, NCHUNK);
    k_basescan<<<1, 1024, 0, stream>>>(btot, base, K);
    k_dinv<<<nblkN, THREADS, 0, stream>>>(deg, dinv, N);
    k_passB<<<NCHUNK, THREADS, 0, stream>>>(eidx, flag, E, C, K, H, base, packed);
    k_gemm1<<<2048, THREADS, 0, stream>>>(x, W1, dinv, g1, N);
    k_bagg1<<<K, THREADS, 0, stream>>>(packed, base, g1, dinv, b1, h1, N);
    k_gemm2<<<2048, THREADS, 0, stream>>>(h1, W2, dinv, g2, N);
    k_bagg2<<<K, THREADS, 0, stream>>>(packed, base, g2, dinv, b2, out, N);
}

// Round 5
// 2004.034 us; speedup vs baseline: 1.1807x; 1.1807x over previous
//
#include <hip/hip_runtime.h>

#define THREADS 256
#define HTHREADS 512
#define NB 64            // nodes per bucket
#define KMAX 1600        // >= ceil(N/NB)=1563
#define NCHUNK 256       // edge chunks for bucket sort
#define CPB 2            // agg chunks per bucket

// ---------------------------------------------------------------------------
// detect -> zero(deg) -> hist(deg + per-chunk bucket histogram) -> colscan ->
// basescan -> dinv -> passB(packed bucket-sorted edges) ->
// gemm1(g1=(X@W1)*dinv, acc1=g1) -> bagg1(acc1 += neighbor sums, LDS tiles) ->
// gemm2(h=relu(dinv*acc1+b1); g2=(h@W2)*dinv, acc2=g2) -> bagg2(acc2 +=) ->
// final(out = dinv*acc2 + b2)
// packed edge = (src << 6) | (dst & 63); bucket = dst >> 6
//
// ALIAS RULES (R4 bug): a buffer may be aliased only if it is dead BEFORE the
// first kernel that writes the alias. g1 dies at bagg1 -> g2/acc2 carve up
// g1's region (disjoint halves). acc1 is read by gemm2 -> acc2 must NOT
// alias acc1.
// ---------------------------------------------------------------------------

__global__ void k_detect(const int* __restrict__ e32, int* __restrict__ flag) {
    if (blockIdx.x == 0 && threadIdx.x == 0) {
        int st = 2;
        for (int i = 0; i < 64; ++i)
            if (e32[2 * i + 1] != 0) { st = 1; break; }
        *flag = st;
    }
}

__global__ __launch_bounds__(THREADS) void k_zero_int(int* __restrict__ p, int n) {
    int i = blockIdx.x * THREADS + threadIdx.x;
    if (i < n) p[i] = 0;
}

__global__ __launch_bounds__(HTHREADS) void k_hist(const int* __restrict__ eidx,
                                                   const int* __restrict__ flag,
                                                   int E, int C, int K,
                                                   int* __restrict__ deg,
                                                   int* __restrict__ H) {
    __shared__ int hl[KMAX];
    int st = *flag;
    for (int i = threadIdx.x; i < K; i += HTHREADS) hl[i] = 0;
    __syncthreads();
    int s0 = blockIdx.x * C;
    int s1 = min(s0 + C, E);
    for (int e = s0 + threadIdx.x; e < s1; e += HTHREADS) {
        int d = eidx[(size_t)(E + e) * st];
        atomicAdd(&deg[d], 1);
        atomicAdd(&hl[d >> 6], 1);
    }
    __syncthreads();
    for (int i = threadIdx.x; i < K; i += HTHREADS)
        H[(size_t)blockIdx.x * K + i] = hl[i];
}

__global__ __launch_bounds__(THREADS) void k_colscan(int* __restrict__ H,
                                                     int* __restrict__ btot,
                                                     int K, int nchunk) {
    int t = blockIdx.x * THREADS + threadIdx.x;
    if (t >= K) return;
    int run = 0;
    for (int c = 0; c < nchunk; ++c) {
        int v = H[(size_t)c * K + t];
        H[(size_t)c * K + t] = run;
        run += v;
    }
    btot[t] = run;
}

// exclusive scan of K<=2048 bucket totals, single block
__global__ __launch_bounds__(1024) void k_basescan(const int* __restrict__ btot,
                                                   int* __restrict__ base, int K) {
    __shared__ int s0[2048], s1[2048];
    int t = threadIdx.x;
    for (int i = t; i < 2048; i += 1024) s0[i] = (i < K) ? btot[i] : 0;
    __syncthreads();
    int* src = s0; int* dst = s1;
    for (int off = 1; off < 2048; off <<= 1) {
        for (int i = t; i < 2048; i += 1024)
            dst[i] = src[i] + (i >= off ? src[i - off] : 0);
        __syncthreads();
        int* tmp = src; src = dst; dst = tmp;
    }
    for (int i = t; i < 2048; i += 1024)
        if (i < K) base[i] = (i == 0) ? 0 : src[i - 1];
    if (t == 0) base[K] = src[K - 1];
}

__global__ __launch_bounds__(THREADS) void k_dinv(const int* __restrict__ deg,
                                                  float* __restrict__ dinv, int n) {
    int i = blockIdx.x * THREADS + threadIdx.x;
    if (i < n) dinv[i] = rsqrtf((float)deg[i] + 1.0f);
}

__global__ __launch_bounds__(HTHREADS) void k_passB(const int* __restrict__ eidx,
                                                    const int* __restrict__ flag,
                                                    int E, int C, int K,
                                                    const int* __restrict__ H,
                                                    const int* __restrict__ base,
                                                    unsigned int* __restrict__ packed) {
    __shared__ int cur[KMAX];
    int st = *flag;
    for (int i = threadIdx.x; i < K; i += HTHREADS)
        cur[i] = base[i] + H[(size_t)blockIdx.x * K + i];
    __syncthreads();
    int s0 = blockIdx.x * C;
    int s1 = min(s0 + C, E);
    for (int e = s0 + threadIdx.x; e < s1; e += HTHREADS) {
        int s = eidx[(size_t)e * st];
        int d = eidx[(size_t)(E + e) * st];
        int pos = atomicAdd(&cur[d >> 6], 1);
        packed[pos] = ((unsigned)s << 6) | (unsigned)(d & 63);
    }
}

// g1[r,c] = (x[r,:] @ W1[:,c]) * dinv[r];  acc1 = g1 (self-loop seed)
__global__ __launch_bounds__(THREADS) void k_gemm1(const float* __restrict__ x,
                                                   const float* __restrict__ W1,
                                                   const float* __restrict__ dinv,
                                                   float* __restrict__ g1,
                                                   float* __restrict__ acc1, int N) {
    __shared__ float Wl[128 * 64];
    for (int i = threadIdx.x; i < 128 * 64; i += THREADS) Wl[i] = W1[i];
    __syncthreads();
    int c = threadIdx.x & 63;
    int rloc = threadIdx.x >> 6;  // 0..3
    for (int rb = blockIdx.x; rb * 4 < N; rb += gridDim.x) {
        int r = rb * 4 + rloc;
        if (r < N) {
            const float4* xr = (const float4*)(x + (size_t)r * 128);
            float acc = 0.0f;
#pragma unroll
            for (int k4 = 0; k4 < 32; ++k4) {
                float4 xv = xr[k4];
                acc = fmaf(xv.x, Wl[(k4 * 4 + 0) * 64 + c], acc);
                acc = fmaf(xv.y, Wl[(k4 * 4 + 1) * 64 + c], acc);
                acc = fmaf(xv.z, Wl[(k4 * 4 + 2) * 64 + c], acc);
                acc = fmaf(xv.w, Wl[(k4 * 4 + 3) * 64 + c], acc);
            }
            float v = acc * dinv[r];
            g1[(size_t)r * 64 + c] = v;
            acc1[(size_t)r * 64 + c] = v;
        }
    }
}

// bucket-chunk aggregation layer1: LDS tile 64x64, 8-deep ILP gathers,
// coalesced atomic flush to acc1
__global__ __launch_bounds__(THREADS) void k_bagg1(const unsigned int* __restrict__ pk,
                                                   const int* __restrict__ base,
                                                   const float* __restrict__ g1,
                                                   float* __restrict__ acc1, int N) {
    __shared__ float tile[NB * 64];
    for (int i = threadIdx.x; i < NB * 64; i += THREADS) tile[i] = 0.0f;
    __syncthreads();
    int b = blockIdx.x / CPB, c = blockIdx.x % CPB;
    int b0 = base[b];
    int deg = base[b + 1] - b0;
    int beg = b0 + (int)((long)deg * c / CPB);
    int end = b0 + (int)((long)deg * (c + 1) / CPB);
    int lane = threadIdx.x & 63;
    int wv = threadIdx.x >> 6;  // 0..3
    int len = end - beg;
    int per = (len + 3) >> 2;
    int jb = beg + wv * per;
    int je = min(jb + per, end);
    int j = jb;
    for (; j + 8 <= je; j += 8) {
        unsigned e[8];
        float v[8];
#pragma unroll
        for (int u = 0; u < 8; ++u) e[u] = pk[j + u];
#pragma unroll
        for (int u = 0; u < 8; ++u) v[u] = g1[(size_t)(e[u] >> 6) * 64 + lane];
#pragma unroll
        for (int u = 0; u < 8; ++u)
            atomicAdd(&tile[(e[u] & 63u) * 64 + lane], v[u]);
    }
    for (; j < je; ++j) {
        unsigned e = pk[j];
        atomicAdd(&tile[(e & 63u) * 64 + lane], g1[(size_t)(e >> 6) * 64 + lane]);
    }
    __syncthreads();
    int lim = min(NB, N - b * NB) * 64;
    float* dst = acc1 + (size_t)b * NB * 64;
    for (int i = threadIdx.x; i < lim; i += THREADS)
        atomicAdd(&dst[i], tile[i]);
}

// h = relu(dinv[r]*acc1[r,:] + b1); g2[r,c] = (h @ W2[:,c]) * dinv[r]; acc2 = g2
__global__ __launch_bounds__(THREADS) void k_gemm2(const float* __restrict__ acc1,
                                                   const float* __restrict__ W2,
                                                   const float* __restrict__ b1,
                                                   const float* __restrict__ dinv,
                                                   float* __restrict__ g2,
                                                   float* __restrict__ acc2, int N) {
    __shared__ float Wl[64 * 32];
    __shared__ float b1l[64];
    for (int i = threadIdx.x; i < 64 * 32; i += THREADS) Wl[i] = W2[i];
    if (threadIdx.x < 64) b1l[threadIdx.x] = b1[threadIdx.x];
    __syncthreads();
    int c = threadIdx.x & 31;
    int rloc = threadIdx.x >> 5;  // 0..7
    for (int rb = blockIdx.x; rb * 8 < N; rb += gridDim.x) {
        int r = rb * 8 + rloc;
        if (r < N) {
            const float* ar = acc1 + (size_t)r * 64;
            float dr = dinv[r];
            float acc = 0.0f;
#pragma unroll
            for (int k = 0; k < 64; ++k) {
                float h = fmaxf(fmaf(dr, ar[k], b1l[k]), 0.0f);
                acc = fmaf(h, Wl[k * 32 + c], acc);
            }
            float v = acc * dr;
            g2[(size_t)r * 32 + c] = v;
            acc2[(size_t)r * 32 + c] = v;
        }
    }
}

// bucket-chunk aggregation layer2: LDS tile 64x32, half-wave per edge
__global__ __launch_bounds__(THREADS) void k_bagg2(const unsigned int* __restrict__ pk,
                                                   const int* __restrict__ base,
                                                   const float* __restrict__ g2,
                                                   float* __restrict__ acc2, int N) {
    __shared__ float tile[NB * 32];
    for (int i = threadIdx.x; i < NB * 32; i += THREADS) tile[i] = 0.0f;
    __syncthreads();
    int b = blockIdx.x / CPB, c = blockIdx.x % CPB;
    int b0 = base[b];
    int deg = base[b + 1] - b0;
    int beg = b0 + (int)((long)deg * c / CPB);
    int end = b0 + (int)((long)deg * (c + 1) / CPB);
    int lane = threadIdx.x & 31;
    int hw = threadIdx.x >> 5;  // 0..7
    int len = end - beg;
    int per = (len + 7) >> 3;
    int jb = beg + hw * per;
    int je = min(jb + per, end);
    int j = jb;
    for (; j + 8 <= je; j += 8) {
        unsigned e[8];
        float v[8];
#pragma unroll
        for (int u = 0; u < 8; ++u) e[u] = pk[j + u];
#pragma unroll
        for (int u = 0; u < 8; ++u) v[u] = g2[(size_t)(e[u] >> 6) * 32 + lane];
#pragma unroll
        for (int u = 0; u < 8; ++u)
            atomicAdd(&tile[(e[u] & 63u) * 32 + lane], v[u]);
    }
    for (; j < je; ++j) {
        unsigned e = pk[j];
        atomicAdd(&tile[(e & 63u) * 32 + lane], g2[(size_t)(e >> 6) * 32 + lane]);
    }
    __syncthreads();
    int lim = min(NB, N - b * NB) * 32;
    float* dst = acc2 + (size_t)b * NB * 32;
    for (int i = threadIdx.x; i < lim; i += THREADS)
        atomicAdd(&dst[i], tile[i]);
}

// out[v,c] = dinv[v]*acc2[v,c] + b2[c]
__global__ __launch_bounds__(THREADS) void k_final(const float* __restrict__ acc2,
                                                   const float* __restrict__ dinv,
                                                   const float* __restrict__ b2,
                                                   float* __restrict__ out, int N) {
    int total = N * 32;
    int stride = gridDim.x * THREADS;
    for (int i = blockIdx.x * THREADS + threadIdx.x; i < total; i += stride)
        out[i] = fmaf(dinv[i >> 5], acc2[i], b2[i & 31]);
}

extern "C" void kernel_launch(void* const* d_in, const int* in_sizes, int n_in,
                              void* d_out, int out_size, void* d_ws, size_t ws_size,
                              hipStream_t stream) {
    const float* x  = (const float*)d_in[0];
    const int* eidx = (const int*)d_in[1];
    const float* W1 = (const float*)d_in[2];
    const float* b1 = (const float*)d_in[3];
    const float* W2 = (const float*)d_in[4];
    const float* b2 = (const float*)d_in[5];
    float* out = (float*)d_out;

    const int N = in_sizes[0] / 128;   // 100000
    const int E = in_sizes[1] / 2;     // 3200000
    const int K = (N + NB - 1) / NB;   // 1563
    const int C = (E + NCHUNK - 1) / NCHUNK;

    // ws layout, all offsets 64-int aligned
    int* flag   = (int*)d_ws;                           // 64
    int* deg    = flag + 64;                            // 100032
    int* H      = deg + 100032;                         // NCHUNK*K = 400128
    int* btot   = H + (size_t)NCHUNK * 1563;            // 1600
    int* base   = btot + 1600;                          // 1600
    unsigned int* packed = (unsigned int*)(base + 1600);// E
    float* dinv = (float*)(packed + E);                 // 100032
    float* g1   = dinv + 100032;                        // N*64 (region reused below)
    float* acc1 = g1 + (size_t)N * 64;                  // N*64
    // g1 dead after bagg1: carve its region into two disjoint N*32 halves
    float* g2   = g1;                                   // N*32 (first half)
    float* acc2 = g1 + (size_t)N * 32;                  // N*32 (second half)

    int nblkN = (N + THREADS - 1) / THREADS;
    int nblkK = (K + THREADS - 1) / THREADS;

    k_detect<<<1, 64, 0, stream>>>(eidx, flag);
    k_zero_int<<<nblkN, THREADS, 0, stream>>>(deg, N);
    k_hist<<<NCHUNK, HTHREADS, 0, stream>>>(eidx, flag, E, C, K, deg, H);
    k_colscan<<<nblkK, THREADS, 0, stream>>>(H, btot, K, NCHUNK);
    k_basescan<<<1, 1024, 0, stream>>>(btot, base, K);
    k_dinv<<<nblkN, THREADS, 0, stream>>>(deg, dinv, N);
    k_passB<<<NCHUNK, HTHREADS, 0, stream>>>(eidx, flag, E, C, K, H, base, packed);
    k_gemm1<<<2048, THREADS, 0, stream>>>(x, W1, dinv, g1, acc1, N);
    k_bagg1<<<K * CPB, THREADS, 0, stream>>>(packed, base, g1, acc1, N);
    k_gemm2<<<2048, THREADS, 0, stream>>>(acc1, W2, b1, dinv, g2, acc2, N);
    k_bagg2<<<K * CPB, THREADS, 0, stream>>>(packed, base, g2, acc2, N);
    k_final<<<2048, THREADS, 0, stream>>>(acc2, dinv, b2, out, N);
}

// Round 6
// 535.113 us; speedup vs baseline: 4.4217x; 3.7451x over previous
//
#include <hip/hip_runtime.h>
#include <hip/hip_fp16.h>

#define THREADS 256
#define HTHREADS 512
#define NB 64            // nodes per bucket
#define KMAX 1600        // >= ceil(N/NB)=1563
#define NCHUNK 256       // edge chunks for bucket sort

// ---------------------------------------------------------------------------
// detect -> zero(deg) -> hist -> colscan -> basescan -> dinv ->
// passB (packed bucket-sorted edges) -> passC (per-bucket counting sort ->
// node CSR + rowptr) -> gemm1 (g1=(X@W1)*dinv, fp16) ->
// agg1 (wave/node register-gather, h1=relu(dinv*(g1[v]+sum)+b1), fp16) ->
// gemm2 (g2=(h1@W2)*dinv, fp16) -> agg2 (out = dinv*(g2[v]+sum)+b2, fp32)
//
// R5 lesson: LDS-atomic consumers serialize the gather chain (VGPR=20).
// Hot loops here accumulate in REGISTERS; atomics only in cheap prep passes.
// Alias rule (R4): no buffer aliasing at all this round (~60 MB < proven 66).
// ---------------------------------------------------------------------------

__global__ void k_detect(const int* __restrict__ e32, int* __restrict__ flag) {
    if (blockIdx.x == 0 && threadIdx.x == 0) {
        int st = 2;
        for (int i = 0; i < 64; ++i)
            if (e32[2 * i + 1] != 0) { st = 1; break; }
        *flag = st;
    }
}

__global__ __launch_bounds__(THREADS) void k_zero_int(int* __restrict__ p, int n) {
    int i = blockIdx.x * THREADS + threadIdx.x;
    if (i < n) p[i] = 0;
}

__global__ __launch_bounds__(HTHREADS) void k_hist(const int* __restrict__ eidx,
                                                   const int* __restrict__ flag,
                                                   int E, int C, int K,
                                                   int* __restrict__ deg,
                                                   int* __restrict__ H) {
    __shared__ int hl[KMAX];
    int st = *flag;
    for (int i = threadIdx.x; i < K; i += HTHREADS) hl[i] = 0;
    __syncthreads();
    int s0 = blockIdx.x * C;
    int s1 = min(s0 + C, E);
    for (int e = s0 + threadIdx.x; e < s1; e += HTHREADS) {
        int d = eidx[(size_t)(E + e) * st];
        atomicAdd(&deg[d], 1);
        atomicAdd(&hl[d >> 6], 1);
    }
    __syncthreads();
    for (int i = threadIdx.x; i < K; i += HTHREADS)
        H[(size_t)blockIdx.x * K + i] = hl[i];
}

__global__ __launch_bounds__(THREADS) void k_colscan(int* __restrict__ H,
                                                     int* __restrict__ btot,
                                                     int K, int nchunk) {
    int t = blockIdx.x * THREADS + threadIdx.x;
    if (t >= K) return;
    int run = 0;
    for (int c = 0; c < nchunk; ++c) {
        int v = H[(size_t)c * K + t];
        H[(size_t)c * K + t] = run;
        run += v;
    }
    btot[t] = run;
}

// exclusive scan of K<=2048 bucket totals, single block
__global__ __launch_bounds__(1024) void k_basescan(const int* __restrict__ btot,
                                                   int* __restrict__ base, int K) {
    __shared__ int s0[2048], s1[2048];
    int t = threadIdx.x;
    for (int i = t; i < 2048; i += 1024) s0[i] = (i < K) ? btot[i] : 0;
    __syncthreads();
    int* src = s0; int* dst = s1;
    for (int off = 1; off < 2048; off <<= 1) {
        for (int i = t; i < 2048; i += 1024)
            dst[i] = src[i] + (i >= off ? src[i - off] : 0);
        __syncthreads();
        int* tmp = src; src = dst; dst = tmp;
    }
    for (int i = t; i < 2048; i += 1024)
        if (i < K) base[i] = (i == 0) ? 0 : src[i - 1];
    if (t == 0) base[K] = src[K - 1];
}

__global__ __launch_bounds__(THREADS) void k_dinv(const int* __restrict__ deg,
                                                  float* __restrict__ dinv, int n) {
    int i = blockIdx.x * THREADS + threadIdx.x;
    if (i < n) dinv[i] = rsqrtf((float)deg[i] + 1.0f);
}

__global__ __launch_bounds__(HTHREADS) void k_passB(const int* __restrict__ eidx,
                                                    const int* __restrict__ flag,
                                                    int E, int C, int K,
                                                    const int* __restrict__ H,
                                                    const int* __restrict__ base,
                                                    unsigned int* __restrict__ packed) {
    __shared__ int cur[KMAX];
    int st = *flag;
    for (int i = threadIdx.x; i < K; i += HTHREADS)
        cur[i] = base[i] + H[(size_t)blockIdx.x * K + i];
    __syncthreads();
    int s0 = blockIdx.x * C;
    int s1 = min(s0 + C, E);
    for (int e = s0 + threadIdx.x; e < s1; e += HTHREADS) {
        int s = eidx[(size_t)e * st];
        int d = eidx[(size_t)(E + e) * st];
        int pos = atomicAdd(&cur[d >> 6], 1);
        packed[pos] = ((unsigned)s << 6) | (unsigned)(d & 63);
    }
}

// per-bucket counting sort: packed -> csr (src by node), rowptr
// one block per bucket; all csr writes land in this bucket's contiguous range
__global__ __launch_bounds__(THREADS) void k_passC(const unsigned int* __restrict__ pk,
                                                   const int* __restrict__ base,
                                                   int K, int N,
                                                   int* __restrict__ csr,
                                                   int* __restrict__ rowptr) {
    __shared__ int cnt[NB];
    __shared__ int cur[NB];
    int b = blockIdx.x;
    int b0 = base[b], b1e = base[b + 1];
    if (threadIdx.x < NB) cnt[threadIdx.x] = 0;
    __syncthreads();
    for (int e = b0 + threadIdx.x; e < b1e; e += THREADS)
        atomicAdd(&cnt[pk[e] & 63u], 1);
    __syncthreads();
    if (threadIdx.x == 0) {
        int run = b0;
        for (int l = 0; l < NB; ++l) {
            cur[l] = run;
            int v = b * NB + l;
            if (v < N) rowptr[v] = run;
            run += cnt[l];
        }
        if (b == K - 1) rowptr[N] = b1e;
    }
    __syncthreads();
    for (int e = b0 + threadIdx.x; e < b1e; e += THREADS) {
        unsigned p = pk[e];
        int pos = atomicAdd(&cur[p & 63u], 1);
        csr[pos] = (int)(p >> 6);
    }
}

// g1[r,c] = half((x[r,:] @ W1[:,c]) * dinv[r])
__global__ __launch_bounds__(THREADS) void k_gemm1(const float* __restrict__ x,
                                                   const float* __restrict__ W1,
                                                   const float* __restrict__ dinv,
                                                   __half* __restrict__ g1, int N) {
    __shared__ float Wl[128 * 64];
    for (int i = threadIdx.x; i < 128 * 64; i += THREADS) Wl[i] = W1[i];
    __syncthreads();
    int c = threadIdx.x & 63;
    int rloc = threadIdx.x >> 6;  // 0..3
    for (int rb = blockIdx.x; rb * 4 < N; rb += gridDim.x) {
        int r = rb * 4 + rloc;
        if (r < N) {
            const float4* xr = (const float4*)(x + (size_t)r * 128);
            float acc = 0.0f;
#pragma unroll
            for (int k4 = 0; k4 < 32; ++k4) {
                float4 xv = xr[k4];
                acc = fmaf(xv.x, Wl[(k4 * 4 + 0) * 64 + c], acc);
                acc = fmaf(xv.y, Wl[(k4 * 4 + 1) * 64 + c], acc);
                acc = fmaf(xv.z, Wl[(k4 * 4 + 2) * 64 + c], acc);
                acc = fmaf(xv.w, Wl[(k4 * 4 + 3) * 64 + c], acc);
            }
            g1[(size_t)r * 64 + c] = __float2half(acc * dinv[r]);
        }
    }
}

// wave per node, 64 lanes = 64 feats, 8-deep register gather
__global__ __launch_bounds__(THREADS) void k_agg1(const int* __restrict__ rowptr,
                                                  const int* __restrict__ csr,
                                                  const __half* __restrict__ g1,
                                                  const float* __restrict__ dinv,
                                                  const float* __restrict__ b1,
                                                  __half* __restrict__ h1, int N) {
    int v = (blockIdx.x * THREADS + threadIdx.x) >> 6;
    if (v >= N) return;
    int lane = threadIdx.x & 63;
    int beg = rowptr[v], end = rowptr[v + 1];
    float sum = __half2float(g1[(size_t)v * 64 + lane]);
    int j = beg;
    for (; j + 8 <= end; j += 8) {
        int s0 = csr[j + 0], s1 = csr[j + 1], s2 = csr[j + 2], s3 = csr[j + 3];
        int s4 = csr[j + 4], s5 = csr[j + 5], s6 = csr[j + 6], s7 = csr[j + 7];
        __half a0 = g1[(size_t)s0 * 64 + lane];
        __half a1 = g1[(size_t)s1 * 64 + lane];
        __half a2 = g1[(size_t)s2 * 64 + lane];
        __half a3 = g1[(size_t)s3 * 64 + lane];
        __half a4 = g1[(size_t)s4 * 64 + lane];
        __half a5 = g1[(size_t)s5 * 64 + lane];
        __half a6 = g1[(size_t)s6 * 64 + lane];
        __half a7 = g1[(size_t)s7 * 64 + lane];
        float t0 = __half2float(a0) + __half2float(a1);
        float t1 = __half2float(a2) + __half2float(a3);
        float t2 = __half2float(a4) + __half2float(a5);
        float t3 = __half2float(a6) + __half2float(a7);
        sum += (t0 + t1) + (t2 + t3);
    }
    for (; j < end; ++j)
        sum += __half2float(g1[(size_t)csr[j] * 64 + lane]);
    h1[(size_t)v * 64 + lane] =
        __float2half(fmaxf(fmaf(dinv[v], sum, b1[lane]), 0.0f));
}

// g2[r,c] = half((h1[r,:] @ W2[:,c]) * dinv[r])
__global__ __launch_bounds__(THREADS) void k_gemm2(const __half* __restrict__ h1,
                                                   const float* __restrict__ W2,
                                                   const float* __restrict__ dinv,
                                                   __half* __restrict__ g2, int N) {
    __shared__ float Wl[64 * 32];
    for (int i = threadIdx.x; i < 64 * 32; i += THREADS) Wl[i] = W2[i];
    __syncthreads();
    int c = threadIdx.x & 31;
    int rloc = threadIdx.x >> 5;  // 0..7
    for (int rb = blockIdx.x; rb * 8 < N; rb += gridDim.x) {
        int r = rb * 8 + rloc;
        if (r < N) {
            const __half2* ar = (const __half2*)(h1 + (size_t)r * 64);
            float acc = 0.0f;
#pragma unroll
            for (int k2 = 0; k2 < 32; ++k2) {
                float2 hv = __half22float2(ar[k2]);
                acc = fmaf(hv.x, Wl[(2 * k2 + 0) * 32 + c], acc);
                acc = fmaf(hv.y, Wl[(2 * k2 + 1) * 32 + c], acc);
            }
            g2[(size_t)r * 32 + c] = __float2half(acc * dinv[r]);
        }
    }
}

// wave per node; lanes 0-31 = feats of even edges, 32-63 = odd edges;
// shfl_xor(32) combines. 8-deep per half-wave (16 edges in flight).
__global__ __launch_bounds__(THREADS) void k_agg2(const int* __restrict__ rowptr,
                                                  const int* __restrict__ csr,
                                                  const __half* __restrict__ g2,
                                                  const float* __restrict__ dinv,
                                                  const float* __restrict__ b2,
                                                  float* __restrict__ out, int N) {
    int v = (blockIdx.x * THREADS + threadIdx.x) >> 6;
    if (v >= N) return;
    int lane = threadIdx.x & 63;
    int f = lane & 31;
    int par = lane >> 5;  // 0 or 1
    int beg = rowptr[v], end = rowptr[v + 1];
    int m = end - beg;
    float sum = (par == 0) ? __half2float(g2[(size_t)v * 32 + f]) : 0.0f;
    int t = 0;
    for (; 2 * t + 16 <= m; t += 8) {
        int e0 = csr[beg + 2 * (t + 0) + par];
        int e1 = csr[beg + 2 * (t + 1) + par];
        int e2 = csr[beg + 2 * (t + 2) + par];
        int e3 = csr[beg + 2 * (t + 3) + par];
        int e4 = csr[beg + 2 * (t + 4) + par];
        int e5 = csr[beg + 2 * (t + 5) + par];
        int e6 = csr[beg + 2 * (t + 6) + par];
        int e7 = csr[beg + 2 * (t + 7) + par];
        __half a0 = g2[(size_t)e0 * 32 + f];
        __half a1 = g2[(size_t)e1 * 32 + f];
        __half a2 = g2[(size_t)e2 * 32 + f];
        __half a3 = g2[(size_t)e3 * 32 + f];
        __half a4 = g2[(size_t)e4 * 32 + f];
        __half a5 = g2[(size_t)e5 * 32 + f];
        __half a6 = g2[(size_t)e6 * 32 + f];
        __half a7 = g2[(size_t)e7 * 32 + f];
        float t0 = __half2float(a0) + __half2float(a1);
        float t1 = __half2float(a2) + __half2float(a3);
        float t2 = __half2float(a4) + __half2float(a5);
        float t3 = __half2float(a6) + __half2float(a7);
        sum += (t0 + t1) + (t2 + t3);
    }
    for (; 2 * t < m; ++t) {
        int idx = 2 * t + par;
        if (idx < m)
            sum += __half2float(g2[(size_t)csr[beg + idx] * 32 + f]);
    }
    sum += __shfl_xor(sum, 32, 64);
    if (par == 0)
        out[(size_t)v * 32 + f] = fmaf(dinv[v], sum, b2[f]);
}

extern "C" void kernel_launch(void* const* d_in, const int* in_sizes, int n_in,
                              void* d_out, int out_size, void* d_ws, size_t ws_size,
                              hipStream_t stream) {
    const float* x  = (const float*)d_in[0];
    const int* eidx = (const int*)d_in[1];
    const float* W1 = (const float*)d_in[2];
    const float* b1 = (const float*)d_in[3];
    const float* W2 = (const float*)d_in[4];
    const float* b2 = (const float*)d_in[5];
    float* out = (float*)d_out;

    const int N = in_sizes[0] / 128;   // 100000
    const int E = in_sizes[1] / 2;     // 3200000
    const int K = (N + NB - 1) / NB;   // 1563
    const int C = (E + NCHUNK - 1) / NCHUNK;

    // ws layout (ints), no aliasing; total ~60.4 MB
    int* flag   = (int*)d_ws;                            // 64
    int* deg    = flag + 64;                             // 100032
    int* H      = deg + 100032;                          // NCHUNK*1563 = 400128
    int* btot   = H + (size_t)NCHUNK * 1563;             // 1600
    int* base   = btot + 1600;                           // 1664
    unsigned int* packed = (unsigned int*)(base + 1664); // E
    int* csr    = (int*)(packed + E);                    // E
    int* rowptr = csr + E;                               // 100032
    float* dinv = (float*)(rowptr + 100032);             // 100032
    __half* g1  = (__half*)(dinv + 100032);              // N*64 halfs
    __half* h1  = g1 + (size_t)N * 64;                   // N*64 halfs
    __half* g2  = h1 + (size_t)N * 64;                   // N*32 halfs

    int nblkN = (N + THREADS - 1) / THREADS;
    int nblkK = (K + THREADS - 1) / THREADS;
    int nblkW = (N * 64 + THREADS - 1) / THREADS;  // wave-per-node grids

    k_detect<<<1, 64, 0, stream>>>(eidx, flag);
    k_zero_int<<<nblkN, THREADS, 0, stream>>>(deg, N);
    k_hist<<<NCHUNK, HTHREADS, 0, stream>>>(eidx, flag, E, C, K, deg, H);
    k_colscan<<<nblkK, THREADS, 0, stream>>>(H, btot, K, NCHUNK);
    k_basescan<<<1, 1024, 0, stream>>>(btot, base, K);
    k_dinv<<<nblkN, THREADS, 0, stream>>>(deg, dinv, N);
    k_passB<<<NCHUNK, HTHREADS, 0, stream>>>(eidx, flag, E, C, K, H, base, packed);
    k_passC<<<K, THREADS, 0, stream>>>(packed, base, K, N, csr, rowptr);
    k_gemm1<<<2048, THREADS, 0, stream>>>(x, W1, dinv, g1, N);
    k_agg1<<<nblkW, THREADS, 0, stream>>>(rowptr, csr, g1, dinv, b1, h1, N);
    k_gemm2<<<2048, THREADS, 0, stream>>>(h1, W2, dinv, g2, N);
    k_agg2<<<nblkW, THREADS, 0, stream>>>(rowptr, csr, g2, dinv, b2, out, N);
}

// Round 7
// 369.971 us; speedup vs baseline: 6.3953x; 1.4464x over previous
//
#include <hip/hip_runtime.h>
#include <hip/hip_fp16.h>

#define THREADS 256
#define HTHREADS 512
#define NB 256           // nodes per bucket
#define KMAX 400         // >= ceil(N/NB)=391
#define NCHUNK 256       // edge chunks for bucket sort

// ---------------------------------------------------------------------------
// detect -> hist(LDS-only bucket histogram) -> colscan -> basescan ->
// passB (packed bucket-sorted edges) -> passC (per-bucket counting sort ->
// node CSR + rowptr + dinv) -> gemm1 (g1=(X@W1)*dinv, fp16) ->
// agg1 (32-lane/node half2 register-gather, h1=relu(...), fp16) ->
// gemm2 (g2=(h1@W2)*dinv, fp16) -> agg2 (16-lane/node, out fp32)
//
// R6 lesson: global atomicAdd streams bounce lines across the 8 non-coherent
// XCD L2s (k_hist: 101 MB writes for a 400 KB counter array). Degree now
// falls out of passC's LDS counting sort for free — no global atomics left
// on the edge path except bucket-frontier scatters.
// packed edge = (src << 8) | (dst & 255); bucket = dst >> 8
// ---------------------------------------------------------------------------

__global__ void k_detect(const int* __restrict__ e32, int* __restrict__ flag) {
    if (blockIdx.x == 0 && threadIdx.x == 0) {
        int st = 2;
        for (int i = 0; i < 64; ++i)
            if (e32[2 * i + 1] != 0) { st = 1; break; }
        *flag = st;
    }
}

// per-chunk bucket histogram only (no global degree atomics)
__global__ __launch_bounds__(HTHREADS) void k_hist(const int* __restrict__ eidx,
                                                   const int* __restrict__ flag,
                                                   int E, int C, int K,
                                                   int* __restrict__ H) {
    __shared__ int hl[KMAX];
    int st = *flag;
    for (int i = threadIdx.x; i < K; i += HTHREADS) hl[i] = 0;
    __syncthreads();
    int s0 = blockIdx.x * C;
    int s1 = min(s0 + C, E);
    for (int e = s0 + threadIdx.x; e < s1; e += HTHREADS) {
        int d = eidx[(size_t)(E + e) * st];
        atomicAdd(&hl[d >> 8], 1);
    }
    __syncthreads();
    for (int i = threadIdx.x; i < K; i += HTHREADS)
        H[(size_t)blockIdx.x * K + i] = hl[i];
}

__global__ __launch_bounds__(THREADS) void k_colscan(int* __restrict__ H,
                                                     int* __restrict__ btot,
                                                     int K, int nchunk) {
    int t = blockIdx.x * THREADS + threadIdx.x;
    if (t >= K) return;
    int run = 0;
    for (int c = 0; c < nchunk; ++c) {
        int v = H[(size_t)c * K + t];
        H[(size_t)c * K + t] = run;
        run += v;
    }
    btot[t] = run;
}

// exclusive scan of K<=2048 bucket totals, single block
__global__ __launch_bounds__(1024) void k_basescan(const int* __restrict__ btot,
                                                   int* __restrict__ base, int K) {
    __shared__ int s0[2048], s1[2048];
    int t = threadIdx.x;
    for (int i = t; i < 2048; i += 1024) s0[i] = (i < K) ? btot[i] : 0;
    __syncthreads();
    int* src = s0; int* dst = s1;
    for (int off = 1; off < 2048; off <<= 1) {
        for (int i = t; i < 2048; i += 1024)
            dst[i] = src[i] + (i >= off ? src[i - off] : 0);
        __syncthreads();
        int* tmp = src; src = dst; dst = tmp;
    }
    for (int i = t; i < 2048; i += 1024)
        if (i < K) base[i] = (i == 0) ? 0 : src[i - 1];
    if (t == 0) base[K] = src[K - 1];
}

__global__ __launch_bounds__(HTHREADS) void k_passB(const int* __restrict__ eidx,
                                                    const int* __restrict__ flag,
                                                    int E, int C, int K,
                                                    const int* __restrict__ H,
                                                    const int* __restrict__ base,
                                                    unsigned int* __restrict__ packed) {
    __shared__ int cur[KMAX];
    int st = *flag;
    for (int i = threadIdx.x; i < K; i += HTHREADS)
        cur[i] = base[i] + H[(size_t)blockIdx.x * K + i];
    __syncthreads();
    int s0 = blockIdx.x * C;
    int s1 = min(s0 + C, E);
    for (int e = s0 + threadIdx.x; e < s1; e += HTHREADS) {
        int s = eidx[(size_t)e * st];
        int d = eidx[(size_t)(E + e) * st];
        int pos = atomicAdd(&cur[d >> 8], 1);
        packed[pos] = ((unsigned)s << 8) | (unsigned)(d & 255);
    }
}

// per-bucket counting sort: packed -> csr (src by node), rowptr, dinv
__global__ __launch_bounds__(NB) void k_passC(const unsigned int* __restrict__ pk,
                                              const int* __restrict__ base,
                                              int K, int N,
                                              int* __restrict__ csr,
                                              int* __restrict__ rowptr,
                                              float* __restrict__ dinv) {
    __shared__ int cnt[NB];
    __shared__ int scn[NB];
    __shared__ int cur[NB];
    int b = blockIdx.x;
    int b0 = base[b], b1e = base[b + 1];
    int t = threadIdx.x;
    cnt[t] = 0;
    __syncthreads();
    for (int e = b0 + t; e < b1e; e += NB)
        atomicAdd(&cnt[pk[e] & 255u], 1);
    __syncthreads();
    int val = cnt[t];
    scn[t] = val;
    __syncthreads();
    for (int off = 1; off < NB; off <<= 1) {
        int tmp = (t >= off) ? scn[t - off] : 0;
        __syncthreads();
        scn[t] += tmp;
        __syncthreads();
    }
    int excl = b0 + scn[t] - val;
    cur[t] = excl;
    int v = b * NB + t;
    if (v < N) {
        rowptr[v] = excl;
        dinv[v] = rsqrtf((float)val + 1.0f);
    }
    if (b == K - 1 && t == 0) rowptr[N] = b1e;
    __syncthreads();
    for (int e = b0 + t; e < b1e; e += NB) {
        unsigned p = pk[e];
        int pos = atomicAdd(&cur[p & 255u], 1);
        csr[pos] = (int)(p >> 8);
    }
}

// g1[r,c] = half((x[r,:] @ W1[:,c]) * dinv[r])
__global__ __launch_bounds__(THREADS) void k_gemm1(const float* __restrict__ x,
                                                   const float* __restrict__ W1,
                                                   const float* __restrict__ dinv,
                                                   __half* __restrict__ g1, int N) {
    __shared__ float Wl[128 * 64];
    for (int i = threadIdx.x; i < 128 * 64; i += THREADS) Wl[i] = W1[i];
    __syncthreads();
    int c = threadIdx.x & 63;
    int rloc = threadIdx.x >> 6;  // 0..3
    for (int rb = blockIdx.x; rb * 4 < N; rb += gridDim.x) {
        int r = rb * 4 + rloc;
        if (r < N) {
            const float4* xr = (const float4*)(x + (size_t)r * 128);
            float acc = 0.0f;
#pragma unroll
            for (int k4 = 0; k4 < 32; ++k4) {
                float4 xv = xr[k4];
                acc = fmaf(xv.x, Wl[(k4 * 4 + 0) * 64 + c], acc);
                acc = fmaf(xv.y, Wl[(k4 * 4 + 1) * 64 + c], acc);
                acc = fmaf(xv.z, Wl[(k4 * 4 + 2) * 64 + c], acc);
                acc = fmaf(xv.w, Wl[(k4 * 4 + 3) * 64 + c], acc);
            }
            g1[(size_t)r * 64 + c] = __float2half(acc * dinv[r]);
        }
    }
}

// 32 lanes per node, lane f handles half2 feature pair f; 8-deep gather
__global__ __launch_bounds__(THREADS) void k_agg1(const int* __restrict__ rowptr,
                                                  const int* __restrict__ csr,
                                                  const __half* __restrict__ g1h,
                                                  const float* __restrict__ dinv,
                                                  const float* __restrict__ b1,
                                                  __half* __restrict__ h1h, int N) {
    const __half2* g1 = (const __half2*)g1h;
    __half2* h1 = (__half2*)h1h;
    int v = (blockIdx.x * THREADS + threadIdx.x) >> 5;
    if (v >= N) return;
    int f = threadIdx.x & 31;
    int beg = rowptr[v], end = rowptr[v + 1];
    float2 s = __half22float2(g1[(size_t)v * 32 + f]);
    float sx = s.x, sy = s.y;
    int j = beg;
    for (; j + 8 <= end; j += 8) {
        int s0 = csr[j + 0], s1 = csr[j + 1], s2 = csr[j + 2], s3 = csr[j + 3];
        int s4 = csr[j + 4], s5 = csr[j + 5], s6 = csr[j + 6], s7 = csr[j + 7];
        __half2 a0 = g1[(size_t)s0 * 32 + f];
        __half2 a1 = g1[(size_t)s1 * 32 + f];
        __half2 a2 = g1[(size_t)s2 * 32 + f];
        __half2 a3 = g1[(size_t)s3 * 32 + f];
        __half2 a4 = g1[(size_t)s4 * 32 + f];
        __half2 a5 = g1[(size_t)s5 * 32 + f];
        __half2 a6 = g1[(size_t)s6 * 32 + f];
        __half2 a7 = g1[(size_t)s7 * 32 + f];
        float2 f0 = __half22float2(a0), f1 = __half22float2(a1);
        float2 f2 = __half22float2(a2), f3 = __half22float2(a3);
        float2 f4 = __half22float2(a4), f5 = __half22float2(a5);
        float2 f6 = __half22float2(a6), f7 = __half22float2(a7);
        sx += ((f0.x + f1.x) + (f2.x + f3.x)) + ((f4.x + f5.x) + (f6.x + f7.x));
        sy += ((f0.y + f1.y) + (f2.y + f3.y)) + ((f4.y + f5.y) + (f6.y + f7.y));
    }
    for (; j < end; ++j) {
        float2 a = __half22float2(g1[(size_t)csr[j] * 32 + f]);
        sx += a.x; sy += a.y;
    }
    float dr = dinv[v];
    float h0 = fmaxf(fmaf(dr, sx, b1[2 * f + 0]), 0.0f);
    float h1v = fmaxf(fmaf(dr, sy, b1[2 * f + 1]), 0.0f);
    h1[(size_t)v * 32 + f] = __floats2half2_rn(h0, h1v);
}

// g2[r,c] = half((h1[r,:] @ W2[:,c]) * dinv[r])
__global__ __launch_bounds__(THREADS) void k_gemm2(const __half* __restrict__ h1,
                                                   const float* __restrict__ W2,
                                                   const float* __restrict__ dinv,
                                                   __half* __restrict__ g2, int N) {
    __shared__ float Wl[64 * 32];
    for (int i = threadIdx.x; i < 64 * 32; i += THREADS) Wl[i] = W2[i];
    __syncthreads();
    int c = threadIdx.x & 31;
    int rloc = threadIdx.x >> 5;  // 0..7
    for (int rb = blockIdx.x; rb * 8 < N; rb += gridDim.x) {
        int r = rb * 8 + rloc;
        if (r < N) {
            const __half2* ar = (const __half2*)(h1 + (size_t)r * 64);
            float acc = 0.0f;
#pragma unroll
            for (int k2 = 0; k2 < 32; ++k2) {
                float2 hv = __half22float2(ar[k2]);
                acc = fmaf(hv.x, Wl[(2 * k2 + 0) * 32 + c], acc);
                acc = fmaf(hv.y, Wl[(2 * k2 + 1) * 32 + c], acc);
            }
            g2[(size_t)r * 32 + c] = __float2half(acc * dinv[r]);
        }
    }
}

// 16 lanes per node, lane f handles half2 feature pair f; 8-deep gather
__global__ __launch_bounds__(THREADS) void k_agg2(const int* __restrict__ rowptr,
                                                  const int* __restrict__ csr,
                                                  const __half* __restrict__ g2h,
                                                  const float* __restrict__ dinv,
                                                  const float* __restrict__ b2,
                                                  float* __restrict__ out, int N) {
    const __half2* g2 = (const __half2*)g2h;
    int v = (blockIdx.x * THREADS + threadIdx.x) >> 4;
    if (v >= N) return;
    int f = threadIdx.x & 15;
    int beg = rowptr[v], end = rowptr[v + 1];
    float2 s = __half22float2(g2[(size_t)v * 16 + f]);
    float sx = s.x, sy = s.y;
    int j = beg;
    for (; j + 8 <= end; j += 8) {
        int s0 = csr[j + 0], s1 = csr[j + 1], s2 = csr[j + 2], s3 = csr[j + 3];
        int s4 = csr[j + 4], s5 = csr[j + 5], s6 = csr[j + 6], s7 = csr[j + 7];
        __half2 a0 = g2[(size_t)s0 * 16 + f];
        __half2 a1 = g2[(size_t)s1 * 16 + f];
        __half2 a2 = g2[(size_t)s2 * 16 + f];
        __half2 a3 = g2[(size_t)s3 * 16 + f];
        __half2 a4 = g2[(size_t)s4 * 16 + f];
        __half2 a5 = g2[(size_t)s5 * 16 + f];
        __half2 a6 = g2[(size_t)s6 * 16 + f];
        __half2 a7 = g2[(size_t)s7 * 16 + f];
        float2 f0 = __half22float2(a0), f1 = __half22float2(a1);
        float2 f2 = __half22float2(a2), f3 = __half22float2(a3);
        float2 f4 = __half22float2(a4), f5 = __half22float2(a5);
        float2 f6 = __half22float2(a6), f7 = __half22float2(a7);
        sx += ((f0.x + f1.x) + (f2.x + f3.x)) + ((f4.x + f5.x) + (f6.x + f7.x));
        sy += ((f0.y + f1.y) + (f2.y + f3.y)) + ((f4.y + f5.y) + (f6.y + f7.y));
    }
    for (; j < end; ++j) {
        float2 a = __half22float2(g2[(size_t)csr[j] * 16 + f]);
        sx += a.x; sy += a.y;
    }
    float dr = dinv[v];
    float2 o;
    o.x = fmaf(dr, sx, b2[2 * f + 0]);
    o.y = fmaf(dr, sy, b2[2 * f + 1]);
    ((float2*)out)[(size_t)v * 16 + f] = o;
}

extern "C" void kernel_launch(void* const* d_in, const int* in_sizes, int n_in,
                              void* d_out, int out_size, void* d_ws, size_t ws_size,
                              hipStream_t stream) {
    const float* x  = (const float*)d_in[0];
    const int* eidx = (const int*)d_in[1];
    const float* W1 = (const float*)d_in[2];
    const float* b1 = (const float*)d_in[3];
    const float* W2 = (const float*)d_in[4];
    const float* b2 = (const float*)d_in[5];
    float* out = (float*)d_out;

    const int N = in_sizes[0] / 128;   // 100000
    const int E = in_sizes[1] / 2;     // 3200000
    const int K = (N + NB - 1) / NB;   // 391
    const int C = (E + NCHUNK - 1) / NCHUNK;

    // ws layout (ints), no aliasing; total ~59 MB
    int* flag   = (int*)d_ws;                            // 64
    int* H      = flag + 64;                             // NCHUNK*K <= 256*400
    int* btot   = H + (size_t)NCHUNK * 400;              // 400
    int* base   = btot + 400;                            // 448
    unsigned int* packed = (unsigned int*)(base + 448);  // E
    int* csr    = (int*)(packed + E);                    // E
    int* rowptr = csr + E;                               // N+1 (100032)
    float* dinv = (float*)(rowptr + 100032);             // 100032
    __half* g1  = (__half*)(dinv + 100032);              // N*64 halfs
    __half* h1  = g1 + (size_t)N * 64;                   // N*64 halfs
    __half* g2  = h1 + (size_t)N * 64;                   // N*32 halfs

    int nblkK = (K + THREADS - 1) / THREADS;

    k_detect<<<1, 64, 0, stream>>>(eidx, flag);
    k_hist<<<NCHUNK, HTHREADS, 0, stream>>>(eidx, flag, E, C, K, H);
    k_colscan<<<nblkK, THREADS, 0, stream>>>(H, btot, K, NCHUNK);
    k_basescan<<<1, 1024, 0, stream>>>(btot, base, K);
    k_passB<<<NCHUNK, HTHREADS, 0, stream>>>(eidx, flag, E, C, K, H, base, packed);
    k_passC<<<K, NB, 0, stream>>>(packed, base, K, N, csr, rowptr, dinv);
    k_gemm1<<<2048, THREADS, 0, stream>>>(x, W1, dinv, g1, N);
    k_agg1<<<(N * 32 + THREADS - 1) / THREADS, THREADS, 0, stream>>>(rowptr, csr, g1, dinv, b1, h1, N);
    k_gemm2<<<2048, THREADS, 0, stream>>>(h1, W2, dinv, g2, N);
    k_agg2<<<(N * 16 + THREADS - 1) / THREADS, THREADS, 0, stream>>>(rowptr, csr, g2, dinv, b2, out, N);
}